// Round 1
// baseline (420.764 us; speedup 1.0000x reference)
//
#include <hip/hip_runtime.h>

#define K_RBF 32
#define H_DIM 64
#define TBL 4096
#define D_MAX 16.0f
#define N_NODES 49152
#define N_EDGES 786432
#define N_GRAPHS 8
#define NODES_PER_GRAPH (N_NODES / N_GRAPHS)   // 6144
#define BLOCKS_PER_GRAPH 384                   // 98304 edges/graph / 256 threads
#define EV_A3_TO_GPA 160.21766208f

// -------- Kernel 1: tabulate F(d) = e_edge(d) and G(d) = dE/dd ----------
__global__ __launch_bounds__(256) void build_table(
    const float* __restrict__ centers,
    const float* __restrict__ W1, const float* __restrict__ b1,
    const float* __restrict__ W2, const float* __restrict__ b2,
    const float* __restrict__ W3, const float* __restrict__ b3,
    float2* __restrict__ tab)
{
    int i = blockIdx.x * blockDim.x + threadIdx.x;
    if (i >= TBL) return;
    float d = (float)i * (D_MAX / (float)TBL);

    float rbf[K_RBF], rbfp[K_RBF];
#pragma unroll
    for (int k = 0; k < K_RBF; ++k) {
        float t = d - centers[k];
        float e = __expf(-t * t);
        rbf[k]  = e;
        rbfp[k] = -2.f * t * e;        // d(rbf)/dd
    }

    // forward: z2[j] accumulated streaming over h (z1 recomputed in backward,
    // avoids keeping z1[64] live)
    float z2[H_DIM];
#pragma unroll
    for (int j = 0; j < H_DIM; ++j) z2[j] = b2[j];

    for (int h = 0; h < H_DIM; ++h) {
        float a0 = 0.f, a1 = 0.f, a2 = 0.f, a3 = 0.f;
#pragma unroll
        for (int k = 0; k < K_RBF; k += 4) {
            a0 = fmaf(rbf[k + 0], W1[(k + 0) * H_DIM + h], a0);
            a1 = fmaf(rbf[k + 1], W1[(k + 1) * H_DIM + h], a1);
            a2 = fmaf(rbf[k + 2], W1[(k + 2) * H_DIM + h], a2);
            a3 = fmaf(rbf[k + 3], W1[(k + 3) * H_DIM + h], a3);
        }
        float z1h = b1[h] + ((a0 + a1) + (a2 + a3));
        float s   = 1.f / (1.f + __expf(-z1h));
        float h1h = z1h * s;
#pragma unroll
        for (int j = 0; j < H_DIM; ++j)
            z2[j] = fmaf(h1h, W2[h * H_DIM + j], z2[j]);
    }

    // output layer + start backward: convert z2[] in place to dz2[]
    float F = b3[0];
#pragma unroll
    for (int j = 0; j < H_DIM; ++j) {
        float z = z2[j];
        float s = 1.f / (1.f + __expf(-z));
        float w = W3[j];
        F = fmaf(z * s, w, F);
        // dz2 = W3 * silu'(z2),  silu'(z) = s*(1 + z*(1-s))
        z2[j] = w * s * fmaf(z, 1.f - s, 1.f);
    }

    // G = sum_h dz1[h] * u[h],  u[h] = sum_k rbfp[k]*W1[k][h]
    float G = 0.f;
    for (int h = 0; h < H_DIM; ++h) {
        float a0 = 0.f, a1 = 0.f, a2 = 0.f, a3 = 0.f;
#pragma unroll
        for (int j = 0; j < H_DIM; j += 4) {
            a0 = fmaf(z2[j + 0], W2[h * H_DIM + j + 0], a0);
            a1 = fmaf(z2[j + 1], W2[h * H_DIM + j + 1], a1);
            a2 = fmaf(z2[j + 2], W2[h * H_DIM + j + 2], a2);
            a3 = fmaf(z2[j + 3], W2[h * H_DIM + j + 3], a3);
        }
        float dh1h = (a0 + a1) + (a2 + a3);

        float p0 = 0.f, p1 = 0.f, p2 = 0.f, p3 = 0.f;
        float q0 = 0.f, q1 = 0.f, q2 = 0.f, q3 = 0.f;
#pragma unroll
        for (int k = 0; k < K_RBF; k += 4) {
            p0 = fmaf(rbf[k + 0],  W1[(k + 0) * H_DIM + h], p0);
            p1 = fmaf(rbf[k + 1],  W1[(k + 1) * H_DIM + h], p1);
            p2 = fmaf(rbf[k + 2],  W1[(k + 2) * H_DIM + h], p2);
            p3 = fmaf(rbf[k + 3],  W1[(k + 3) * H_DIM + h], p3);
            q0 = fmaf(rbfp[k + 0], W1[(k + 0) * H_DIM + h], q0);
            q1 = fmaf(rbfp[k + 1], W1[(k + 1) * H_DIM + h], q1);
            q2 = fmaf(rbfp[k + 2], W1[(k + 2) * H_DIM + h], q2);
            q3 = fmaf(rbfp[k + 3], W1[(k + 3) * H_DIM + h], q3);
        }
        float z1h  = b1[h] + ((p0 + p1) + (p2 + p3));
        float uh   = (q0 + q1) + (q2 + q3);
        float s    = 1.f / (1.f + __expf(-z1h));
        float dz1h = dh1h * s * fmaf(z1h, 1.f - s, 1.f);
        G = fmaf(dz1h, uh, G);
    }

    tab[i] = make_float2(F, G);
}

// -------- Kernel 2: per-edge lookup + scatter ----------
__global__ __launch_bounds__(256) void edge_kernel(
    const float* __restrict__ pos, const float* __restrict__ bond,
    const int* __restrict__ src, const int* __restrict__ dst,
    const float* __restrict__ volume, const float2* __restrict__ tab,
    float* __restrict__ out)
{
    __shared__ float2 stab[TBL];          // 32 KB
    __shared__ float  red[4][10];

    {
        const float4* t4 = (const float4*)tab;
        float4* s4 = (float4*)stab;
#pragma unroll
        for (int q = 0; q < (TBL / 2) / 256; ++q)
            s4[q * 256 + threadIdx.x] = t4[q * 256 + threadIdx.x];
    }
    __syncthreads();

    // XCD swizzle: graph g -> blockIdx % 8 -> XCD g (L2 locality for pos
    // gathers and force atomics; perf heuristic only)
    int lb = (blockIdx.x & 7) * BLOCKS_PER_GRAPH + (blockIdx.x >> 3);
    int g  = blockIdx.x & 7;
    int e  = lb * 256 + threadIdx.x;

    int si = src[e], di = dst[e];
    float bx = bond[3 * e + 0], by = bond[3 * e + 1], bz = bond[3 * e + 2];
    float dx = bx + pos[3 * di + 0] - pos[3 * si + 0];
    float dy = by + pos[3 * di + 1] - pos[3 * si + 1];
    float dz = bz + pos[3 * di + 2] - pos[3 * si + 2];
    float ss = fmaf(dx, dx, fmaf(dy, dy, fmaf(dz, dz, 1e-12f)));
    float d  = sqrtf(ss);

    float tt  = fminf(d * ((float)TBL / D_MAX), (float)(TBL - 1));
    int   idx = min((int)tt, TBL - 2);
    float fr  = tt - (float)idx;
    float2 ta = stab[idx], tb = stab[idx + 1];
    float F = fmaf(fr, tb.x - ta.x, ta.x);
    float G = fmaf(fr, tb.y - ta.y, ta.y);

    float scl = G / d;                       // ddisp = (dE/dd)/d * disp = gbv
    float gx = scl * dx, gy = scl * dy, gz = scl * dz;

    // forces = -gpos: dst gets -ddisp, src gets +ddisp
    float* forces = out + N_GRAPHS;
    atomicAdd(forces + 3 * di + 0, -gx);
    atomicAdd(forces + 3 * di + 1, -gy);
    atomicAdd(forces + 3 * di + 2, -gz);
    atomicAdd(forces + 3 * si + 0,  gx);
    atomicAdd(forces + 3 * si + 1,  gy);
    atomicAdd(forces + 3 * si + 2,  gz);

    // per-wave reduce: energy + 9 stress components (bond_a * ddisp_b;
    // stresses = -EV*S/vol with S = sum bond x f_ij, f_ij = -ddisp
    //          = +EV * sum(bond x ddisp) / vol)
    float v[10] = { F,
                    bx * gx, bx * gy, bx * gz,
                    by * gx, by * gy, by * gz,
                    bz * gx, bz * gy, bz * gz };
#pragma unroll
    for (int q = 0; q < 10; ++q) {
        float x = v[q];
#pragma unroll
        for (int m = 32; m > 0; m >>= 1) x += __shfl_xor(x, m, 64);
        v[q] = x;
    }
    int wave = threadIdx.x >> 6;
    if ((threadIdx.x & 63) == 0) {
#pragma unroll
        for (int q = 0; q < 10; ++q) red[wave][q] = v[q];
    }
    __syncthreads();
    if (threadIdx.x < 10) {
        float tot = red[0][threadIdx.x] + red[1][threadIdx.x]
                  + red[2][threadIdx.x] + red[3][threadIdx.x];
        if (threadIdx.x == 0) {
            atomicAdd(out + g, tot);                       // energies[g]
        } else {
            float vol = volume[g * NODES_PER_GRAPH];
            atomicAdd(out + N_GRAPHS + 3 * N_NODES + g * 9 + (threadIdx.x - 1),
                      tot * (EV_A3_TO_GPA / vol));
        }
    }
    // hessian slot (last float) stays 0 from the memset
}

extern "C" void kernel_launch(void* const* d_in, const int* in_sizes, int n_in,
                              void* d_out, int out_size, void* d_ws, size_t ws_size,
                              hipStream_t stream)
{
    const float* pos     = (const float*)d_in[0];
    const float* bond    = (const float*)d_in[1];
    const int*   src     = (const int*)d_in[2];
    const int*   dst     = (const int*)d_in[3];
    // d_in[4] = edge_graph (implicit: edges are contiguous per graph)
    const float* volume  = (const float*)d_in[5];
    const float* centers = (const float*)d_in[6];
    const float* W1 = (const float*)d_in[7];
    const float* b1 = (const float*)d_in[8];
    const float* W2 = (const float*)d_in[9];
    const float* b2 = (const float*)d_in[10];
    const float* W3 = (const float*)d_in[11];
    const float* b3 = (const float*)d_in[12];
    float*  out = (float*)d_out;
    float2* tab = (float2*)d_ws;   // 32 KB of scratch

    hipMemsetAsync(d_out, 0, (size_t)out_size * sizeof(float), stream);
    build_table<<<TBL / 256, 256, 0, stream>>>(centers, W1, b1, W2, b2, W3, b3, tab);
    edge_kernel<<<N_EDGES / 256, 256, 0, stream>>>(pos, bond, src, dst, volume, tab, out);
}

// Round 2
// 362.162 us; speedup vs baseline: 1.1618x; 1.1618x over previous
//
#include <hip/hip_runtime.h>
#include <math.h>

#define K_RBF 32
#define H_DIM 64
#define TBL 4096
#define D_MAX 16.0f
#define N_NODES 49152
#define N_EDGES 786432
#define N_GRAPHS 8
#define NODES_PER_GRAPH (N_NODES / N_GRAPHS)   // 6144
#define BLOCKS_PER_GRAPH 384                   // 98304 edges/graph / 256 threads
#define EV_A3_TO_GPA 160.21766208f
#define FBUF_LEN (N_NODES * 3)                 // floats per XCD-private force buffer
#define LOG2E 1.44269504088896f

// -------- Kernel 1: tabulate F(d)=e_edge(d), G(d)=dE/dd — wave-per-entry ----
// 64 lanes cooperate on one table entry: lane = hidden index h (and j).
// W2 staged in LDS with stride 65 so both row-major (z2 accumulation) and
// transposed (dh1 accumulation) reads are bank-conflict-free (2 lanes/bank
// is free on gfx950 — m136).
__global__ __launch_bounds__(256) void build_table(
    const float* __restrict__ centers,
    const float* __restrict__ W1, const float* __restrict__ b1,
    const float* __restrict__ W2, const float* __restrict__ b2,
    const float* __restrict__ W3, const float* __restrict__ b3,
    float2* __restrict__ tab)
{
    __shared__ float W2s[H_DIM * 65];
    for (int idx = threadIdx.x; idx < H_DIM * H_DIM; idx += 256)
        W2s[(idx >> 6) * 65 + (idx & 63)] = W2[idx];
    __syncthreads();

    int lane = threadIdx.x & 63;
    int i    = blockIdx.x * 4 + (threadIdx.x >> 6);
    float d  = (float)i * (D_MAX / (float)TBL);

    // lane h: z1[h] = b1[h] + sum_k rbf(k)*W1[k][h]; u[h] = sum_k rbf'(k)*W1[k][h]
    float z1 = b1[lane], u = 0.f;
#pragma unroll
    for (int k = 0; k < K_RBF; ++k) {
        float t = d - centers[k];              // wave-uniform (s_load)
        float e = exp2f(-t * t * LOG2E);       // exp(-t^2)
        float w = W1[k * H_DIM + lane];        // coalesced
        z1 = fmaf(e, w, z1);
        u  = fmaf(-2.f * t * e, w, u);
    }
    float s1  = 1.f / (1.f + exp2f(-z1 * LOG2E));
    float h1  = z1 * s1;
    float ds1 = s1 * fmaf(z1, 1.f - s1, 1.f);  // silu'(z1)

    // lane j: z2[j] = b2[j] + sum_h h1[h]*W2[h][j]
    float z2 = b2[lane];
#pragma unroll
    for (int h = 0; h < H_DIM; ++h)
        z2 = fmaf(__shfl(h1, h, 64), W2s[h * 65 + lane], z2);

    float s2 = 1.f / (1.f + exp2f(-z2 * LOG2E));
    float w3 = W3[lane];
    float Fp = z2 * s2 * w3;                       // silu(z2[j]) * W3[j]
    float dz2 = w3 * s2 * fmaf(z2, 1.f - s2, 1.f); // W3[j]*silu'(z2[j])

    // lane h: dh1[h] = sum_j dz2[j] * W2[h][j]  (transposed read, padded LDS)
    float dh1 = 0.f;
#pragma unroll
    for (int j = 0; j < H_DIM; ++j)
        dh1 = fmaf(__shfl(dz2, j, 64), W2s[lane * 65 + j], dh1);

    float Gp = dh1 * ds1 * u;                      // dz1[h] * u[h]

#pragma unroll
    for (int m = 32; m > 0; m >>= 1) {
        Fp += __shfl_xor(Fp, m, 64);
        Gp += __shfl_xor(Gp, m, 64);
    }
    if (lane == 0) tab[i] = make_float2(Fp + b3[0], Gp);
}

// -------- Kernel 2: per-edge lookup + scatter ----------
// PRIV=true: forces accumulate into per-XCD private buffers with
// workgroup-scope atomics (RMW stays in the local TCC — no fabric traffic);
// buffer selected by the HARDWARE XCC_ID so the mapping is exact, not a
// dispatch heuristic. PRIV=false: round-1 device-scope fallback.
template <bool PRIV>
__global__ __launch_bounds__(256) void edge_kernel(
    const float* __restrict__ pos, const float* __restrict__ bond,
    const int* __restrict__ src, const int* __restrict__ dst,
    const float* __restrict__ volume, const float2* __restrict__ tab,
    float* __restrict__ fbuf, float* __restrict__ out)
{
    __shared__ float2 stab[TBL];          // 32 KB
    __shared__ float  red[4][10];

    {
        const float4* t4 = (const float4*)tab;
        float4* s4 = (float4*)stab;
#pragma unroll
        for (int q = 0; q < (TBL / 2) / 256; ++q)
            s4[q * 256 + threadIdx.x] = t4[q * 256 + threadIdx.x];
    }
    __syncthreads();

    // XCD swizzle: graph g -> blockIdx % 8 (L2 locality heuristic for pos)
    int lb = (blockIdx.x & 7) * BLOCKS_PER_GRAPH + (blockIdx.x >> 3);
    int g  = blockIdx.x & 7;
    int e  = lb * 256 + threadIdx.x;

    int si = src[e], di = dst[e];
    float bx = bond[3 * e + 0], by = bond[3 * e + 1], bz = bond[3 * e + 2];
    float dx = bx + pos[3 * di + 0] - pos[3 * si + 0];
    float dy = by + pos[3 * di + 1] - pos[3 * si + 1];
    float dz = bz + pos[3 * di + 2] - pos[3 * si + 2];
    float ss = fmaf(dx, dx, fmaf(dy, dy, fmaf(dz, dz, 1e-12f)));
    float d  = sqrtf(ss);

    float tt  = fminf(d * ((float)TBL / D_MAX), (float)(TBL - 1));
    int   idx = min((int)tt, TBL - 2);
    float fr  = tt - (float)idx;
    float2 ta = stab[idx], tb = stab[idx + 1];
    float F = fmaf(fr, tb.x - ta.x, ta.x);
    float G = fmaf(fr, tb.y - ta.y, ta.y);

    float scl = G / d;                       // gbv = (dE/dd)/d * disp
    float gx = scl * dx, gy = scl * dy, gz = scl * dz;

    if (PRIV) {
        unsigned xcc;
        asm volatile("s_getreg_b32 %0, hwreg(HW_REG_XCC_ID)" : "=s"(xcc));
        float* fb = fbuf + (size_t)(xcc & 7) * FBUF_LEN;
        __hip_atomic_fetch_add(fb + 3 * di + 0, -gx, __ATOMIC_RELAXED, __HIP_MEMORY_SCOPE_WORKGROUP);
        __hip_atomic_fetch_add(fb + 3 * di + 1, -gy, __ATOMIC_RELAXED, __HIP_MEMORY_SCOPE_WORKGROUP);
        __hip_atomic_fetch_add(fb + 3 * di + 2, -gz, __ATOMIC_RELAXED, __HIP_MEMORY_SCOPE_WORKGROUP);
        __hip_atomic_fetch_add(fb + 3 * si + 0,  gx, __ATOMIC_RELAXED, __HIP_MEMORY_SCOPE_WORKGROUP);
        __hip_atomic_fetch_add(fb + 3 * si + 1,  gy, __ATOMIC_RELAXED, __HIP_MEMORY_SCOPE_WORKGROUP);
        __hip_atomic_fetch_add(fb + 3 * si + 2,  gz, __ATOMIC_RELAXED, __HIP_MEMORY_SCOPE_WORKGROUP);
    } else {
        float* forces = out + N_GRAPHS;
        atomicAdd(forces + 3 * di + 0, -gx);
        atomicAdd(forces + 3 * di + 1, -gy);
        atomicAdd(forces + 3 * di + 2, -gz);
        atomicAdd(forces + 3 * si + 0,  gx);
        atomicAdd(forces + 3 * si + 1,  gy);
        atomicAdd(forces + 3 * si + 2,  gz);
    }

    // energy + 9 stress components; stresses = +EV * sum(bond (x) gbv) / vol
    float v[10] = { F,
                    bx * gx, bx * gy, bx * gz,
                    by * gx, by * gy, by * gz,
                    bz * gx, bz * gy, bz * gz };
#pragma unroll
    for (int q = 0; q < 10; ++q) {
        float x = v[q];
#pragma unroll
        for (int m = 32; m > 0; m >>= 1) x += __shfl_xor(x, m, 64);
        v[q] = x;
    }
    int wave = threadIdx.x >> 6;
    if ((threadIdx.x & 63) == 0) {
#pragma unroll
        for (int q = 0; q < 10; ++q) red[wave][q] = v[q];
    }
    __syncthreads();
    if (threadIdx.x < 10) {
        float tot = red[0][threadIdx.x] + red[1][threadIdx.x]
                  + red[2][threadIdx.x] + red[3][threadIdx.x];
        if (threadIdx.x == 0) {
            atomicAdd(out + g, tot);                       // energies[g]
        } else {
            float vol = volume[g * NODES_PER_GRAPH];
            atomicAdd(out + N_GRAPHS + 3 * N_NODES + g * 9 + (threadIdx.x - 1),
                      tot * (EV_A3_TO_GPA / vol));
        }
    }
    // hessian slot stays 0 from the memset
}

// -------- Kernel 3: sum the 8 per-XCD buffers into out.forces ----------
__global__ __launch_bounds__(256) void reduce_forces(
    const float* __restrict__ fbuf, float* __restrict__ out)
{
    int t = blockIdx.x * 256 + threadIdx.x;   // < FBUF_LEN
    float s = 0.f;
#pragma unroll
    for (int x = 0; x < 8; ++x) s += fbuf[(size_t)x * FBUF_LEN + t];
    out[N_GRAPHS + t] = s;
}

extern "C" void kernel_launch(void* const* d_in, const int* in_sizes, int n_in,
                              void* d_out, int out_size, void* d_ws, size_t ws_size,
                              hipStream_t stream)
{
    const float* pos     = (const float*)d_in[0];
    const float* bond    = (const float*)d_in[1];
    const int*   src     = (const int*)d_in[2];
    const int*   dst     = (const int*)d_in[3];
    // d_in[4] = edge_graph (implicit: edges contiguous per graph)
    const float* volume  = (const float*)d_in[5];
    const float* centers = (const float*)d_in[6];
    const float* W1 = (const float*)d_in[7];
    const float* b1 = (const float*)d_in[8];
    const float* W2 = (const float*)d_in[9];
    const float* b2 = (const float*)d_in[10];
    const float* W3 = (const float*)d_in[11];
    const float* b3 = (const float*)d_in[12];
    float*  out  = (float*)d_out;
    float2* tab  = (float2*)d_ws;                       // 32 KB
    float*  fbuf = (float*)((char*)d_ws + TBL * 8);     // 8 x 576 KB

    size_t need = (size_t)TBL * 8 + (size_t)8 * FBUF_LEN * 4;
    bool priv = ws_size >= need;

    hipMemsetAsync(d_out, 0, (size_t)out_size * sizeof(float), stream);
    if (priv)
        hipMemsetAsync(fbuf, 0, (size_t)8 * FBUF_LEN * 4, stream);

    build_table<<<TBL / 4, 256, 0, stream>>>(centers, W1, b1, W2, b2, W3, b3, tab);

    if (priv) {
        edge_kernel<true><<<N_EDGES / 256, 256, 0, stream>>>(
            pos, bond, src, dst, volume, tab, fbuf, out);
        reduce_forces<<<FBUF_LEN / 256, 256, 0, stream>>>(fbuf, out);
    } else {
        edge_kernel<false><<<N_EDGES / 256, 256, 0, stream>>>(
            pos, bond, src, dst, volume, tab, fbuf, out);
    }
}

// Round 3
// 357.898 us; speedup vs baseline: 1.1757x; 1.0119x over previous
//
#include <hip/hip_runtime.h>
#include <math.h>

#define K_RBF 32
#define H_DIM 64
#define TBL 4096
#define D_MAX 16.0f
#define N_NODES 49152
#define N_EDGES 786432
#define N_GRAPHS 8
#define NODES_PER_GRAPH (N_NODES / N_GRAPHS)   // 6144
#define BLOCKS_PER_GRAPH 384                   // 98304 edges/graph / 256 threads
#define EV_A3_TO_GPA 160.21766208f
#define FBUF_LEN (N_NODES * 3)                 // floats per XCD-private force buffer
#define LOG2E 1.44269504088896f
// out layout: energies[8] | forces[147456] | stresses[72] | hessian[1]
#define OUT_FORCES   N_GRAPHS
#define OUT_STRESS   (N_GRAPHS + 3 * N_NODES)  // 147464
#define OUT_TAIL_N   81                        // 8 energies + 72 stress + 1 hessian

// Raw L2-cached atomic: no sc0/sc1 -> RMW executes in the LOCAL XCD's TCC,
// write-back cached. Correct only when every RMW to this address comes from
// the same XCD (per-XCD buffers indexed by hw XCC_ID). Visibility to the
// next dispatch is the standard kernel-boundary L2 release.
__device__ __forceinline__ void atomic_add_l2(float* p, float v) {
    asm volatile("global_atomic_add_f32 %0, %1, off"
                 :: "v"(p), "v"(v) : "memory");
}

// -------- Kernel 1: tabulate F(d)=e_edge(d), G(d)=dE/dd — wave-per-entry ----
__global__ __launch_bounds__(256) void build_table(
    const float* __restrict__ centers,
    const float* __restrict__ W1, const float* __restrict__ b1,
    const float* __restrict__ W2, const float* __restrict__ b2,
    const float* __restrict__ W3, const float* __restrict__ b3,
    float2* __restrict__ tab, float* __restrict__ out, int zero_out_tail)
{
    // block 0 zeroes the small out fields (energies/stress/hessian) so the
    // priv path needs no d_out memset; forces region is overwritten later.
    if (blockIdx.x == 0 && zero_out_tail) {
        int t = threadIdx.x;
        if (t < N_GRAPHS) out[t] = 0.f;
        else if (t < OUT_TAIL_N) out[3 * N_NODES + t] = 0.f;  // 147456+8..147456+80
    }

    __shared__ float W2s[H_DIM * 65];
    for (int idx = threadIdx.x; idx < H_DIM * H_DIM; idx += 256)
        W2s[(idx >> 6) * 65 + (idx & 63)] = W2[idx];
    __syncthreads();

    int lane = threadIdx.x & 63;
    int i    = blockIdx.x * 4 + (threadIdx.x >> 6);
    float d  = (float)i * (D_MAX / (float)TBL);

    float z1 = b1[lane], u = 0.f;
#pragma unroll
    for (int k = 0; k < K_RBF; ++k) {
        float t = d - centers[k];
        float e = exp2f(-t * t * LOG2E);       // exp(-t^2)
        float w = W1[k * H_DIM + lane];
        z1 = fmaf(e, w, z1);
        u  = fmaf(-2.f * t * e, w, u);
    }
    float s1  = 1.f / (1.f + exp2f(-z1 * LOG2E));
    float h1  = z1 * s1;
    float ds1 = s1 * fmaf(z1, 1.f - s1, 1.f);

    float z2 = b2[lane];
#pragma unroll
    for (int h = 0; h < H_DIM; ++h)
        z2 = fmaf(__shfl(h1, h, 64), W2s[h * 65 + lane], z2);

    float s2 = 1.f / (1.f + exp2f(-z2 * LOG2E));
    float w3 = W3[lane];
    float Fp  = z2 * s2 * w3;
    float dz2 = w3 * s2 * fmaf(z2, 1.f - s2, 1.f);

    float dh1 = 0.f;
#pragma unroll
    for (int j = 0; j < H_DIM; ++j)
        dh1 = fmaf(__shfl(dz2, j, 64), W2s[lane * 65 + j], dh1);

    float Gp = dh1 * ds1 * u;

#pragma unroll
    for (int m = 32; m > 0; m >>= 1) {
        Fp += __shfl_xor(Fp, m, 64);
        Gp += __shfl_xor(Gp, m, 64);
    }
    if (lane == 0) tab[i] = make_float2(Fp + b3[0], Gp);
}

// -------- Kernel 2: per-edge lookup + scatter ----------
template <bool PRIV>
__global__ __launch_bounds__(256) void edge_kernel(
    const float* __restrict__ pos, const float* __restrict__ bond,
    const int* __restrict__ src, const int* __restrict__ dst,
    const float* __restrict__ volume, const float2* __restrict__ tab,
    float* __restrict__ fbuf, float* __restrict__ out)
{
    __shared__ float2 stab[TBL];          // 32 KB
    __shared__ float  red[4][10];

    {
        const float4* t4 = (const float4*)tab;
        float4* s4 = (float4*)stab;
#pragma unroll
        for (int q = 0; q < (TBL / 2) / 256; ++q)
            s4[q * 256 + threadIdx.x] = t4[q * 256 + threadIdx.x];
    }
    __syncthreads();

    int lb = (blockIdx.x & 7) * BLOCKS_PER_GRAPH + (blockIdx.x >> 3);
    int g  = blockIdx.x & 7;
    int e  = lb * 256 + threadIdx.x;

    int si = src[e], di = dst[e];
    float bx = bond[3 * e + 0], by = bond[3 * e + 1], bz = bond[3 * e + 2];
    float dx = bx + pos[3 * di + 0] - pos[3 * si + 0];
    float dy = by + pos[3 * di + 1] - pos[3 * si + 1];
    float dz = bz + pos[3 * di + 2] - pos[3 * si + 2];
    float ss = fmaf(dx, dx, fmaf(dy, dy, fmaf(dz, dz, 1e-12f)));
    float d  = sqrtf(ss);

    float tt  = fminf(d * ((float)TBL / D_MAX), (float)(TBL - 1));
    int   idx = min((int)tt, TBL - 2);
    float fr  = tt - (float)idx;
    float2 ta = stab[idx], tb = stab[idx + 1];
    float F = fmaf(fr, tb.x - ta.x, ta.x);
    float G = fmaf(fr, tb.y - ta.y, ta.y);

    float scl = G / d;                       // gbv = (dE/dd)/d * disp
    float gx = scl * dx, gy = scl * dy, gz = scl * dz;

    if (PRIV) {
        unsigned xcc;
        asm volatile("s_getreg_b32 %0, hwreg(HW_REG_XCC_ID)" : "=s"(xcc));
        float* fb = fbuf + (size_t)(xcc & 7) * FBUF_LEN;
        atomic_add_l2(fb + 3 * di + 0, -gx);
        atomic_add_l2(fb + 3 * di + 1, -gy);
        atomic_add_l2(fb + 3 * di + 2, -gz);
        atomic_add_l2(fb + 3 * si + 0,  gx);
        atomic_add_l2(fb + 3 * si + 1,  gy);
        atomic_add_l2(fb + 3 * si + 2,  gz);
    } else {
        float* forces = out + OUT_FORCES;
        atomicAdd(forces + 3 * di + 0, -gx);
        atomicAdd(forces + 3 * di + 1, -gy);
        atomicAdd(forces + 3 * di + 2, -gz);
        atomicAdd(forces + 3 * si + 0,  gx);
        atomicAdd(forces + 3 * si + 1,  gy);
        atomicAdd(forces + 3 * si + 2,  gz);
    }

    // energy + 9 stress components; stresses = +EV * sum(bond (x) gbv) / vol
    float v[10] = { F,
                    bx * gx, bx * gy, bx * gz,
                    by * gx, by * gy, by * gz,
                    bz * gx, bz * gy, bz * gz };
#pragma unroll
    for (int q = 0; q < 10; ++q) {
        float x = v[q];
#pragma unroll
        for (int m = 32; m > 0; m >>= 1) x += __shfl_xor(x, m, 64);
        v[q] = x;
    }
    int wave = threadIdx.x >> 6;
    if ((threadIdx.x & 63) == 0) {
#pragma unroll
        for (int q = 0; q < 10; ++q) red[wave][q] = v[q];
    }
    __syncthreads();
    if (threadIdx.x < 10) {
        float tot = red[0][threadIdx.x] + red[1][threadIdx.x]
                  + red[2][threadIdx.x] + red[3][threadIdx.x];
        if (threadIdx.x == 0) {
            atomicAdd(out + g, tot);                       // energies[g]
        } else {
            float vol = volume[g * NODES_PER_GRAPH];
            atomicAdd(out + OUT_STRESS + g * 9 + (threadIdx.x - 1),
                      tot * (EV_A3_TO_GPA / vol));
        }
    }
    // hessian slot stays 0 (zeroed in build_table / memset)
}

// -------- Kernel 3: sum the 8 per-XCD buffers into out.forces ----------
__global__ __launch_bounds__(256) void reduce_forces(
    const float* __restrict__ fbuf, float* __restrict__ out)
{
    int t = blockIdx.x * 256 + threadIdx.x;   // < FBUF_LEN
    float s = 0.f;
#pragma unroll
    for (int x = 0; x < 8; ++x) s += fbuf[(size_t)x * FBUF_LEN + t];
    out[OUT_FORCES + t] = s;
}

extern "C" void kernel_launch(void* const* d_in, const int* in_sizes, int n_in,
                              void* d_out, int out_size, void* d_ws, size_t ws_size,
                              hipStream_t stream)
{
    const float* pos     = (const float*)d_in[0];
    const float* bond    = (const float*)d_in[1];
    const int*   src     = (const int*)d_in[2];
    const int*   dst     = (const int*)d_in[3];
    // d_in[4] = edge_graph (implicit: edges contiguous per graph)
    const float* volume  = (const float*)d_in[5];
    const float* centers = (const float*)d_in[6];
    const float* W1 = (const float*)d_in[7];
    const float* b1 = (const float*)d_in[8];
    const float* W2 = (const float*)d_in[9];
    const float* b2 = (const float*)d_in[10];
    const float* W3 = (const float*)d_in[11];
    const float* b3 = (const float*)d_in[12];
    float*  out  = (float*)d_out;
    float2* tab  = (float2*)d_ws;                       // 32 KB
    float*  fbuf = (float*)((char*)d_ws + TBL * 8);     // 8 x 576 KB

    size_t need = (size_t)TBL * 8 + (size_t)8 * FBUF_LEN * 4;
    bool priv = ws_size >= need;

    if (priv) {
        hipMemsetAsync(fbuf, 0, (size_t)8 * FBUF_LEN * 4, stream);
        build_table<<<TBL / 4, 256, 0, stream>>>(centers, W1, b1, W2, b2, W3, b3,
                                                 tab, out, 1);
        edge_kernel<true><<<N_EDGES / 256, 256, 0, stream>>>(
            pos, bond, src, dst, volume, tab, fbuf, out);
        reduce_forces<<<FBUF_LEN / 256, 256, 0, stream>>>(fbuf, out);
    } else {
        hipMemsetAsync(d_out, 0, (size_t)out_size * sizeof(float), stream);
        build_table<<<TBL / 4, 256, 0, stream>>>(centers, W1, b1, W2, b2, W3, b3,
                                                 tab, out, 0);
        edge_kernel<false><<<N_EDGES / 256, 256, 0, stream>>>(
            pos, bond, src, dst, volume, tab, fbuf, out);
    }
}

// Round 4
// 190.300 us; speedup vs baseline: 2.2111x; 1.8807x over previous
//
#include <hip/hip_runtime.h>
#include <math.h>

#define K_RBF 32
#define H_DIM 64
#define TBL 4096
#define D_MAX 16.0f
#define N_NODES 49152
#define N_EDGES 786432
#define N_GRAPHS 8
#define NODES_PER_GRAPH (N_NODES / N_GRAPHS)   // 6144
#define BLOCKS_PER_GRAPH 384                   // 98304 edges/graph / 256 threads
#define EV_A3_TO_GPA 160.21766208f
#define LOG2E 1.44269504088896f

// out layout: energies[8] | forces[147456] | stresses[72] | hessian[1]
#define OUT_FORCES   N_GRAPHS
#define OUT_STRESS   (N_GRAPHS + 3 * N_NODES)  // 147464
#define OUT_TAIL_N   81

// force-scatter binning: chunk = node >> 12 (4096 nodes -> 48 KB LDS acc)
#define CHUNK_NODES  4096
#define CHUNK_FLOATS (CHUNK_NODES * 3)         // 12288 floats / 48 KB
#define N_CHUNKS     12                        // 49152 / 4096
#define NB_SLICES    16                        // partial buffers per chunk
#define REC_CAP      147456                    // per-chunk record capacity
                                               // (expected 131072; +12.5% = ~45 sigma)
// ws offsets (bytes)
#define OFF_TAB   0u
#define OFF_CNT   32768u                       // 12 ints (pad to 256 B)
#define OFF_REC   33024u                       // 12 * REC_CAP * 16 B
#define OFF_PART  (33024u + 12u * REC_CAP * 16u)      // 12*16*48 KB
#define WS_NEED   (OFF_PART + (size_t)N_CHUNKS * NB_SLICES * CHUNK_FLOATS * 4u)

// -------- Kernel 1: tabulate F(d)=e_edge(d), G(d)=dE/dd — wave-per-entry ----
__global__ __launch_bounds__(256) void build_table(
    const float* __restrict__ centers,
    const float* __restrict__ W1, const float* __restrict__ b1,
    const float* __restrict__ W2, const float* __restrict__ b2,
    const float* __restrict__ W3, const float* __restrict__ b3,
    float2* __restrict__ tab, float* __restrict__ out, int zero_out_tail)
{
    // block 0 zeroes energies/stress/hessian (forces are fully overwritten
    // by reduce_forces in the main path).
    if (blockIdx.x == 0 && zero_out_tail) {
        int t = threadIdx.x;
        if (t < N_GRAPHS) out[t] = 0.f;
        else if (t < OUT_TAIL_N) out[3 * N_NODES + t] = 0.f;
    }

    __shared__ float W2s[H_DIM * 65];
    for (int idx = threadIdx.x; idx < H_DIM * H_DIM; idx += 256)
        W2s[(idx >> 6) * 65 + (idx & 63)] = W2[idx];
    __syncthreads();

    int lane = threadIdx.x & 63;
    int i    = blockIdx.x * 4 + (threadIdx.x >> 6);
    float d  = (float)i * (D_MAX / (float)TBL);

    float z1 = b1[lane], u = 0.f;
#pragma unroll
    for (int k = 0; k < K_RBF; ++k) {
        float t = d - centers[k];
        float e = exp2f(-t * t * LOG2E);       // exp(-t^2)
        float w = W1[k * H_DIM + lane];
        z1 = fmaf(e, w, z1);
        u  = fmaf(-2.f * t * e, w, u);
    }
    float s1  = 1.f / (1.f + exp2f(-z1 * LOG2E));
    float h1  = z1 * s1;
    float ds1 = s1 * fmaf(z1, 1.f - s1, 1.f);

    float z2 = b2[lane];
#pragma unroll
    for (int h = 0; h < H_DIM; ++h)
        z2 = fmaf(__shfl(h1, h, 64), W2s[h * 65 + lane], z2);

    float s2 = 1.f / (1.f + exp2f(-z2 * LOG2E));
    float w3 = W3[lane];
    float Fp  = z2 * s2 * w3;
    float dz2 = w3 * s2 * fmaf(z2, 1.f - s2, 1.f);

    float dh1 = 0.f;
#pragma unroll
    for (int j = 0; j < H_DIM; ++j)
        dh1 = fmaf(__shfl(dz2, j, 64), W2s[lane * 65 + j], dh1);

    float Gp = dh1 * ds1 * u;

#pragma unroll
    for (int m = 32; m > 0; m >>= 1) {
        Fp += __shfl_xor(Fp, m, 64);
        Gp += __shfl_xor(Gp, m, 64);
    }
    if (lane == 0) tab[i] = make_float2(Fp + b3[0], Gp);
}

// -------- Kernel 2a: per-edge compute + record emission (NO force atomics) --
__global__ __launch_bounds__(256) void edge_compute(
    const float* __restrict__ pos, const float* __restrict__ bond,
    const int* __restrict__ src, const int* __restrict__ dst,
    const float* __restrict__ volume, const float2* __restrict__ tab,
    float4* __restrict__ recs, int* __restrict__ gcnt,
    float* __restrict__ out)
{
    __shared__ float2 stab[TBL];          // 32 KB
    __shared__ float  red[4][10];
    __shared__ int    cnt[N_CHUNKS];
    __shared__ int    base[N_CHUNKS];

    {
        const float4* t4 = (const float4*)tab;
        float4* s4 = (float4*)stab;
#pragma unroll
        for (int q = 0; q < (TBL / 2) / 256; ++q)
            s4[q * 256 + threadIdx.x] = t4[q * 256 + threadIdx.x];
    }
    if (threadIdx.x < N_CHUNKS) cnt[threadIdx.x] = 0;
    __syncthreads();

    // graph swizzle (edges contiguous per graph)
    int lb = (blockIdx.x & 7) * BLOCKS_PER_GRAPH + (blockIdx.x >> 3);
    int g  = blockIdx.x & 7;
    int e  = lb * 256 + threadIdx.x;

    int si = src[e], di = dst[e];
    float bx = bond[3 * e + 0], by = bond[3 * e + 1], bz = bond[3 * e + 2];
    float dx = bx + pos[3 * di + 0] - pos[3 * si + 0];
    float dy = by + pos[3 * di + 1] - pos[3 * si + 1];
    float dz = bz + pos[3 * di + 2] - pos[3 * si + 2];
    float ss = fmaf(dx, dx, fmaf(dy, dy, fmaf(dz, dz, 1e-12f)));
    float d  = sqrtf(ss);

    float tt  = fminf(d * ((float)TBL / D_MAX), (float)(TBL - 1));
    int   idx = min((int)tt, TBL - 2);
    float fr  = tt - (float)idx;
    float2 ta = stab[idx], tb = stab[idx + 1];
    float F = fmaf(fr, tb.x - ta.x, ta.x);
    float G = fmaf(fr, tb.y - ta.y, ta.y);

    float scl = G / d;                       // gbv = (dE/dd)/d * disp
    float gx = scl * dx, gy = scl * dy, gz = scl * dz;

    // two records: dst gets -g, src gets +g (forces = -gpos)
    int b0 = di >> 12, l0 = di & (CHUNK_NODES - 1);
    int b1 = si >> 12, l1 = si & (CHUNK_NODES - 1);
    int s0 = atomicAdd(&cnt[b0], 1);
    int s1 = atomicAdd(&cnt[b1], 1);
    __syncthreads();
    if (threadIdx.x < N_CHUNKS)
        base[threadIdx.x] = atomicAdd(&gcnt[threadIdx.x], cnt[threadIdx.x]);
    __syncthreads();
    {
        int p0 = base[b0] + s0;
        int p1 = base[b1] + s1;
        if (p0 < REC_CAP)
            recs[(size_t)b0 * REC_CAP + p0] =
                make_float4(-gx, -gy, -gz, __int_as_float(l0));
        if (p1 < REC_CAP)
            recs[(size_t)b1 * REC_CAP + p1] =
                make_float4(gx, gy, gz, __int_as_float(l1));
    }

    // energy + 9 stress components; stresses = +EV * sum(bond (x) gbv) / vol
    float v[10] = { F,
                    bx * gx, bx * gy, bx * gz,
                    by * gx, by * gy, by * gz,
                    bz * gx, bz * gy, bz * gz };
#pragma unroll
    for (int q = 0; q < 10; ++q) {
        float x = v[q];
#pragma unroll
        for (int m = 32; m > 0; m >>= 1) x += __shfl_xor(x, m, 64);
        v[q] = x;
    }
    int wave = threadIdx.x >> 6;
    if ((threadIdx.x & 63) == 0) {
#pragma unroll
        for (int q = 0; q < 10; ++q) red[wave][q] = v[q];
    }
    __syncthreads();
    if (threadIdx.x < 10) {
        float tot = red[0][threadIdx.x] + red[1][threadIdx.x]
                  + red[2][threadIdx.x] + red[3][threadIdx.x];
        if (threadIdx.x == 0) {
            atomicAdd(out + g, tot);
        } else {
            float vol = volume[g * NODES_PER_GRAPH];
            atomicAdd(out + OUT_STRESS + g * 9 + (threadIdx.x - 1),
                      tot * (EV_A3_TO_GPA / vol));
        }
    }
}

// -------- Kernel 2b: per-chunk LDS accumulation of records ----------
__global__ __launch_bounds__(512) void scatter_forces(
    const float4* __restrict__ recs, const int* __restrict__ gcnt,
    float* __restrict__ partials)
{
    __shared__ float acc[CHUNK_FLOATS];    // 48 KB
    int chunk = blockIdx.x >> 4;           // /NB_SLICES
    int slice = blockIdx.x & (NB_SLICES - 1);

    {
        float4* a4 = (float4*)acc;
#pragma unroll
        for (int q = 0; q < (CHUNK_FLOATS / 4) / 512; ++q)
            a4[q * 512 + threadIdx.x] = make_float4(0.f, 0.f, 0.f, 0.f);
    }
    __syncthreads();

    int total = min(gcnt[chunk], REC_CAP);
    int start = (int)(((long long)total * slice) / NB_SLICES);
    int end   = (int)(((long long)total * (slice + 1)) / NB_SLICES);
    const float4* seg = recs + (size_t)chunk * REC_CAP;

    for (int r = start + threadIdx.x; r < end; r += 512) {
        float4 rec = seg[r];
        int li = 3 * __float_as_int(rec.w);
        atomicAdd(&acc[li + 0], rec.x);
        atomicAdd(&acc[li + 1], rec.y);
        atomicAdd(&acc[li + 2], rec.z);
    }
    __syncthreads();

    float4* pp = (float4*)(partials + (size_t)blockIdx.x * CHUNK_FLOATS);
    float4* a4 = (float4*)acc;
#pragma unroll
    for (int q = 0; q < (CHUNK_FLOATS / 4) / 512; ++q)
        pp[q * 512 + threadIdx.x] = a4[q * 512 + threadIdx.x];
}

// -------- Kernel 3: sum slice-partials into out.forces ----------
__global__ __launch_bounds__(256) void reduce_forces(
    const float* __restrict__ partials, float* __restrict__ out)
{
    int f = blockIdx.x * 256 + threadIdx.x;   // < 3*N_NODES
    int chunk = f / CHUNK_FLOATS;
    int off   = f - chunk * CHUNK_FLOATS;
    const float* pp = partials + (size_t)chunk * NB_SLICES * CHUNK_FLOATS + off;
    float s = 0.f;
#pragma unroll
    for (int k = 0; k < NB_SLICES; ++k) s += pp[(size_t)k * CHUNK_FLOATS];
    out[OUT_FORCES + f] = s;
}

// -------- Fallback: round-1 device-scope atomic path (small ws) ----------
__global__ __launch_bounds__(256) void edge_fallback(
    const float* __restrict__ pos, const float* __restrict__ bond,
    const int* __restrict__ src, const int* __restrict__ dst,
    const float* __restrict__ volume, const float2* __restrict__ tab,
    float* __restrict__ out)
{
    __shared__ float2 stab[TBL];
    __shared__ float  red[4][10];
    {
        const float4* t4 = (const float4*)tab;
        float4* s4 = (float4*)stab;
#pragma unroll
        for (int q = 0; q < (TBL / 2) / 256; ++q)
            s4[q * 256 + threadIdx.x] = t4[q * 256 + threadIdx.x];
    }
    __syncthreads();

    int lb = (blockIdx.x & 7) * BLOCKS_PER_GRAPH + (blockIdx.x >> 3);
    int g  = blockIdx.x & 7;
    int e  = lb * 256 + threadIdx.x;

    int si = src[e], di = dst[e];
    float bx = bond[3 * e + 0], by = bond[3 * e + 1], bz = bond[3 * e + 2];
    float dx = bx + pos[3 * di + 0] - pos[3 * si + 0];
    float dy = by + pos[3 * di + 1] - pos[3 * si + 1];
    float dz = bz + pos[3 * di + 2] - pos[3 * si + 2];
    float d  = sqrtf(fmaf(dx, dx, fmaf(dy, dy, fmaf(dz, dz, 1e-12f))));

    float tt  = fminf(d * ((float)TBL / D_MAX), (float)(TBL - 1));
    int   idx = min((int)tt, TBL - 2);
    float fr  = tt - (float)idx;
    float2 ta = stab[idx], tb = stab[idx + 1];
    float F = fmaf(fr, tb.x - ta.x, ta.x);
    float G = fmaf(fr, tb.y - ta.y, ta.y);
    float scl = G / d;
    float gx = scl * dx, gy = scl * dy, gz = scl * dz;

    float* forces = out + OUT_FORCES;
    atomicAdd(forces + 3 * di + 0, -gx);
    atomicAdd(forces + 3 * di + 1, -gy);
    atomicAdd(forces + 3 * di + 2, -gz);
    atomicAdd(forces + 3 * si + 0,  gx);
    atomicAdd(forces + 3 * si + 1,  gy);
    atomicAdd(forces + 3 * si + 2,  gz);

    float v[10] = { F,
                    bx * gx, bx * gy, bx * gz,
                    by * gx, by * gy, by * gz,
                    bz * gx, bz * gy, bz * gz };
#pragma unroll
    for (int q = 0; q < 10; ++q) {
        float x = v[q];
#pragma unroll
        for (int m = 32; m > 0; m >>= 1) x += __shfl_xor(x, m, 64);
        v[q] = x;
    }
    int wave = threadIdx.x >> 6;
    if ((threadIdx.x & 63) == 0)
#pragma unroll
        for (int q = 0; q < 10; ++q) red[wave][q] = v[q];
    __syncthreads();
    if (threadIdx.x < 10) {
        float tot = red[0][threadIdx.x] + red[1][threadIdx.x]
                  + red[2][threadIdx.x] + red[3][threadIdx.x];
        if (threadIdx.x == 0) atomicAdd(out + g, tot);
        else {
            float vol = volume[g * NODES_PER_GRAPH];
            atomicAdd(out + OUT_STRESS + g * 9 + (threadIdx.x - 1),
                      tot * (EV_A3_TO_GPA / vol));
        }
    }
}

extern "C" void kernel_launch(void* const* d_in, const int* in_sizes, int n_in,
                              void* d_out, int out_size, void* d_ws, size_t ws_size,
                              hipStream_t stream)
{
    const float* pos     = (const float*)d_in[0];
    const float* bond    = (const float*)d_in[1];
    const int*   src     = (const int*)d_in[2];
    const int*   dst     = (const int*)d_in[3];
    // d_in[4] = edge_graph (implicit: edges contiguous per graph)
    const float* volume  = (const float*)d_in[5];
    const float* centers = (const float*)d_in[6];
    const float* W1 = (const float*)d_in[7];
    const float* b1 = (const float*)d_in[8];
    const float* W2 = (const float*)d_in[9];
    const float* b2 = (const float*)d_in[10];
    const float* W3 = (const float*)d_in[11];
    const float* b3 = (const float*)d_in[12];
    float*  out  = (float*)d_out;
    char*   ws   = (char*)d_ws;
    float2* tab  = (float2*)(ws + OFF_TAB);
    int*    gcnt = (int*)(ws + OFF_CNT);
    float4* recs = (float4*)(ws + OFF_REC);
    float*  part = (float*)(ws + OFF_PART);

    if (ws_size >= WS_NEED) {
        hipMemsetAsync(gcnt, 0, 256, stream);
        build_table<<<TBL / 4, 256, 0, stream>>>(centers, W1, b1, W2, b2, W3, b3,
                                                 tab, out, 1);
        edge_compute<<<N_EDGES / 256, 256, 0, stream>>>(
            pos, bond, src, dst, volume, tab, recs, gcnt, out);
        scatter_forces<<<N_CHUNKS * NB_SLICES, 512, 0, stream>>>(recs, gcnt, part);
        reduce_forces<<<(3 * N_NODES) / 256, 256, 0, stream>>>(part, out);
    } else {
        hipMemsetAsync(d_out, 0, (size_t)out_size * sizeof(float), stream);
        build_table<<<TBL / 4, 256, 0, stream>>>(centers, W1, b1, W2, b2, W3, b3,
                                                 tab, out, 0);
        edge_fallback<<<N_EDGES / 256, 256, 0, stream>>>(
            pos, bond, src, dst, volume, tab, out);
    }
}